// Round 13
// baseline (43.098 us; speedup 1.0000x reference)
//
#include <hip/hip_runtime.h>
#include <cmath>

#define MATSZ 262144  // 2048 * 128
#define QKV_OFF 0     // qkv[3][64][512][8]; Q pre-scaled by log2(e)/sqrt(8)

// ---------------- k_qkvq: QKV projection + quantum closed form ---------------
// thread = (col e, K-half); W row fragment in regs (issued before staging
// barrier); x rows broadcast from LDS; K-halves combined via LDS partials.
// grid (256,3) = 768 blocks = 3/CU. Also zeroes `out` for the atomic scatter.
__global__ __launch_bounds__(256, 3) void k_qkvq(
    const float* __restrict__ x, const float* __restrict__ Wq,
    const float* __restrict__ Wk, const float* __restrict__ Wv,
    const float* __restrict__ qp, float* __restrict__ ws,
    float* __restrict__ out) {
  __shared__ float xs[8][128];     // 4 KB
  __shared__ float th[2][8][128];  // 8 KB partial sums per K-half
  const int t = threadIdx.x;
  const int tile = blockIdx.x;  // 0..255 (8 rows each)
  const int m = blockIdx.y;     // 0..2
  {  // zero the output buffer (atomic scatter target), 2048*128 floats
    int gid = (m * 256 + tile) * 256 + t;  // 0..196607
    if (gid < 131072) ((float2*)out)[gid] = make_float2(0.f, 0.f);
  }
  const float* W = (m == 0) ? Wq : (m == 1) ? Wk : Wv;
  const int e = t & 127, half = t >> 7;
  float4 w[16];
  {
    const float4* wr = (const float4*)W + (size_t)e * 32 + half * 16;
#pragma unroll
    for (int i = 0; i < 16; ++i) w[i] = wr[i];  // in flight during staging
  }
  ((float4*)&xs[0][0])[t] = ((const float4*)(x + (size_t)tile * 1024))[t];
  __syncthreads();
  const float4* xs4 = (const float4*)&xs[0][0];
#pragma unroll
  for (int r = 0; r < 8; ++r) {
    float a = 0.f;
    const float4* xr = xs4 + r * 32 + half * 16;
#pragma unroll
    for (int i = 0; i < 16; ++i) {
      float4 xv = xr[i];  // LDS broadcast (wave-uniform addr)
      a = fmaf(xv.x, w[i].x, a);
      a = fmaf(xv.y, w[i].y, a);
      a = fmaf(xv.z, w[i].z, a);
      a = fmaf(xv.w, w[i].w, a);
    }
    th[half][r][e] = a;  // lanes e-consecutive: conflict-free
  }
  __syncthreads();
  // quantum tail: thread = (row rg, half-head cg); cols 4cg..4cg+3.
  const int cg = t & 31, rg = t >> 5;
  const float4* th4 = (const float4*)&th[0][0][0];
  float4 s0 = th4[rg * 32 + cg];
  float4 s1 = th4[256 + rg * 32 + cg];
  float4 a4 = make_float4(s0.x + s1.x, s0.y + s1.y, s0.z + s1.z, s0.w + s1.w);
  const int j0 = (cg & 1) * 4;
  float4 qs;
  qs.x = qp[j0 + 0] + qp[8 + j0 + 0];
  qs.y = qp[j0 + 1] + qp[8 + j0 + 1];
  qs.z = qp[j0 + 2] + qp[8 + j0 + 2];
  qs.w = qp[j0 + 3] + qp[8 + j0 + 3];
  float4 c;
  c.x = __cosf(a4.x + qs.x);
  c.y = __cosf(a4.y + qs.y);
  c.z = __cosf(a4.z + qs.z);
  c.w = __cosf(a4.w + qs.w);
  float4 u;  // local prefix: (c0, c1, c0c2, c1c3) in this half's numbering
  u.x = c.x; u.y = c.y; u.z = c.x * c.z; u.w = c.y * c.w;
  float gz = __shfl_xor(u.z, 1);  // even lane's (c0*c2) -> odd lane
  float gw = __shfl_xor(u.w, 1);  // even lane's (c1*c3) -> odd lane
  const bool hi = (cg & 1) != 0;
  float mz = hi ? gz : 1.f, mw = hi ? gw : 1.f;
  const float osc = (m == 0) ? 0.51013389376f : 1.0f;  // log2e/sqrt(8) into Q
  float4 o;
  o.x = u.x * mz * osc; o.y = u.y * mw * osc;
  o.z = u.z * mz * osc; o.w = u.w * mw * osc;
  const int h = cg >> 1;
  int row = tile * 8 + rg;
  int b = row >> 9, s = row & 511;
  float* dst = ws + QKV_OFF + (size_t)m * MATSZ +
               ((size_t)((b << 4) + h) * 512 + s) * 8 + (hi ? 4 : 0);
  *(float4*)dst = o;
}

// ---------------- k_attn: attention + split-K out-projection scatter ---------
// grid (16,64) = 1024 blocks = 4/CU [R5 proven geometry]. 256 thr = 16 qslots
// (2 rows) x 16 k-parts. After attention, the block's [32 rows x 8 cols] slice
// contributes a rank-8 update to out[32][128] via atomicAdd (split-K over the
// 16 heads; total FMA identical to the old k_out dispatch).
__global__ __launch_bounds__(256, 4) void k_attn(
    const float* __restrict__ ws, const float* __restrict__ Wo,
    float* __restrict__ out) {
  __shared__ float4 kslo[512], kshi[512], vslo[512], vshi[512];  // 32 KB
  __shared__ float aout_s[32][8];                                // 1 KB
  const int qt = blockIdx.x;  // 0..15 (32 rows)
  const int bh = blockIdx.y;  // 0..63
  const int b = bh >> 4, h = bh & 15;
  const float* qkv = ws + QKV_OFF;
  const float* Qg = qkv + (size_t)bh * 4096;
  const float4* Kg = (const float4*)(qkv + MATSZ + (size_t)bh * 4096);
  const float4* Vg = (const float4*)(qkv + 2 * (size_t)MATSZ + (size_t)bh * 4096);
  const int t = threadIdx.x;
  for (int k = t; k < 512; k += 256) {
    kslo[k] = Kg[2 * k]; kshi[k] = Kg[2 * k + 1];
    vslo[k] = Vg[2 * k]; vshi[k] = Vg[2 * k + 1];
  }
  __syncthreads();
  const int qslot = t >> 4, ko = t & 15;
  const int row0 = qt * 32 + qslot * 2;  // local s of first of 2 q rows
  float4 qa[2], qb[2];  // Q pre-scaled by log2e/sqrt(8) in k_qkvq
#pragma unroll
  for (int r = 0; r < 2; ++r) {
    qa[r] = ((const float4*)(Qg + (size_t)(row0 + r) * 8))[0];
    qb[r] = ((const float4*)(Qg + (size_t)(row0 + r) * 8))[1];
  }
  float l[2] = {0.f, 0.f};
  float a[2][8];
#pragma unroll
  for (int r = 0; r < 2; ++r)
#pragma unroll
    for (int j = 0; j < 8; ++j) a[r][j] = 0.f;
#pragma unroll 4
  for (int i = 0; i < 32; ++i) {
    int k = i * 16 + ko;  // 16 distinct addrs x 4-way broadcast: conflict-free
    float4 kx = kslo[k], ky = kshi[k];
    float4 vx = vslo[k], vy = vshi[k];
#pragma unroll
    for (int r = 0; r < 2; ++r) {
      float s = qa[r].x * kx.x + qa[r].y * kx.y + qa[r].z * kx.z +
                qa[r].w * kx.w + qb[r].x * ky.x + qb[r].y * ky.y +
                qb[r].z * ky.z + qb[r].w * ky.w;
      float p = exp2f(s);  // |orig score| <= 2.83: no max subtraction
      l[r] += p;
      a[r][0] = fmaf(p, vx.x, a[r][0]);
      a[r][1] = fmaf(p, vx.y, a[r][1]);
      a[r][2] = fmaf(p, vx.z, a[r][2]);
      a[r][3] = fmaf(p, vx.w, a[r][3]);
      a[r][4] = fmaf(p, vy.x, a[r][4]);
      a[r][5] = fmaf(p, vy.y, a[r][5]);
      a[r][6] = fmaf(p, vy.z, a[r][6]);
      a[r][7] = fmaf(p, vy.w, a[r][7]);
    }
  }
#pragma unroll
  for (int mm = 1; mm <= 8; mm <<= 1) {  // reduce over 16 k-parts (in-wave)
#pragma unroll
    for (int r = 0; r < 2; ++r) {
      l[r] += __shfl_xor(l[r], mm);
#pragma unroll
      for (int j = 0; j < 8; ++j) a[r][j] += __shfl_xor(a[r][j], mm);
    }
  }
  if (ko == 0) {  // park normalized slice in LDS (2-way write alias = free)
#pragma unroll
    for (int r = 0; r < 2; ++r) {
      float inv = 1.f / l[r];
      float* d = &aout_s[qslot * 2 + r][0];
      ((float4*)d)[0] = make_float4(a[r][0] * inv, a[r][1] * inv,
                                    a[r][2] * inv, a[r][3] * inv);
      ((float4*)d)[1] = make_float4(a[r][4] * inv, a[r][5] * inv,
                                    a[r][6] * inv, a[r][7] * inv);
    }
  }
  __syncthreads();
  // rank-8 scatter: thread = (col e, j-half); pairs (t, t^1) share e.
  const int e = t >> 1, jh = (t & 1) * 4;
  const float4 wv = *(const float4*)(Wo + (size_t)e * 128 + h * 8 + jh);
  float* obase = out + ((size_t)(b * 512 + qt * 32)) * 128 + e;
#pragma unroll 4
  for (int row = 0; row < 32; ++row) {
    const float4 av = *(const float4*)&aout_s[row][jh];  // broadcast
    float p = av.x * wv.x + av.y * wv.y + av.z * wv.z + av.w * wv.w;
    p += __shfl_xor(p, 1);  // combine j-halves
    if ((t & 1) == 0) atomicAdd(obase + (size_t)row * 128, p);
  }
}

extern "C" void kernel_launch(void* const* d_in, const int* in_sizes, int n_in,
                              void* d_out, int out_size, void* d_ws, size_t ws_size,
                              hipStream_t stream) {
  const float* x  = (const float*)d_in[0];
  const float* Wq = (const float*)d_in[1];
  const float* Wk = (const float*)d_in[2];
  const float* Wv = (const float*)d_in[3];
  const float* Wo = (const float*)d_in[4];
  const float* qp = (const float*)d_in[5];
  float* out = (float*)d_out;
  float* ws = (float*)d_ws;

  hipLaunchKernelGGL(k_qkvq, dim3(256, 3), dim3(256), 0, stream,
                     x, Wq, Wk, Wv, qp, ws, out);
  hipLaunchKernelGGL(k_attn, dim3(16, 64), dim3(256), 0, stream,
                     ws, Wo, out);
}